// Round 6
// baseline (22.237 us; speedup 1.0000x reference)
//
#include <hip/hip_runtime.h>

constexpr int N = 512;
constexpr int D = 128;
constexpr int A = 4;            // anchors per block
constexpr int NBLK = N / A;     // 128 blocks
constexpr float MARGIN = 1.0f;
constexpr float EPS_T = 1e-16f;

// Two deterministic kernels. Main: 4 anchors per block, 512 threads.
//  P1: stage 4 anchor embeddings; stream all 512 rows ONCE (coalesced,
//      8 lanes per row) computing 4 distances per row -> drow[4][N].
//      Cuts total L2 traffic 128 MB -> 32 MB vs 1-anchor blocks.
//  P2: waves 0..3 each ballot-compact one anchor's positive distances.
//  P3: per thread: k = tid; for each anchor, hinge over ~16 positives.
//  P4: fixed-tree f64 reduction of the fused (sum,npos,ntrip) triple.
// Final: 128 threads reduce the 128 triples, write the two scalars.
__global__ __launch_bounds__(512) void triplet_main_k(
    const float* __restrict__ emb, const int* __restrict__ labels,
    double* __restrict__ partial)
{
    __shared__ float  ei[A][D];
    __shared__ float  drow[A][N];
    __shared__ float  posd[A][N];
    __shared__ int    npos_s[A];
    __shared__ double red[24];   // [0..7]=sum, [8..15]=npos, [16..23]=ntrip

    const int i0   = blockIdx.x * A;
    const int tid  = threadIdx.x;
    const int lane = tid & 63;
    const int wid  = tid >> 6;

    // stage anchors: thread tid -> ei[tid>>7][tid&127], coalesced
    ei[tid >> 7][tid & (D - 1)] = emb[(size_t)i0 * D + tid];
    const int lk = labels[tid];                  // this thread's k-label
    int liA[A];
    #pragma unroll
    for (int a = 0; a < A; ++a) liA[a] = labels[i0 + a];   // uniform broadcasts
    __syncthreads();

    // ---- P1: coalesced distance rows, 4 anchors at once ----
    const int sub = tid & 7;                     // 8 lanes per row
    #pragma unroll 2
    for (int p = 0; p < 8; ++p) {
        const int r = p * 64 + (tid >> 3);
        const float4* er = reinterpret_cast<const float4*>(emb + (size_t)r * D);
        float4 v[4];
        #pragma unroll
        for (int c = 0; c < 4; ++c) v[c] = er[sub + 8 * c];
        #pragma unroll
        for (int a = 0; a < A; ++a) {
            const float4* ea = reinterpret_cast<const float4*>(ei[a]);
            float sq = 0.f;
            #pragma unroll
            for (int c = 0; c < 4; ++c) {
                const float4 w = ea[sub + 8 * c];
                float d0 = w.x - v[c].x, d1 = w.y - v[c].y;
                float d2 = w.z - v[c].z, d3 = w.w - v[c].w;
                sq += d0 * d0 + d1 * d1 + d2 * d2 + d3 * d3;
            }
            sq += __shfl_xor(sq, 1);
            sq += __shfl_xor(sq, 2);
            sq += __shfl_xor(sq, 4);
            if (sub == 0) drow[a][r] = (sq > 0.f) ? sqrtf(sq) : 0.f;  // safe sqrt
        }
    }
    __syncthreads();

    // ---- P2: waves 0..3 compact positives for anchor = wid ----
    if (wid < A) {
        const int ia = i0 + wid;
        const int li = liA[wid];
        int base = 0;
        #pragma unroll
        for (int r = 0; r < 8; ++r) {
            const int j = r * 64 + lane;
            const bool pred = (labels[j] == li) && (j != ia);
            const unsigned long long m = __ballot(pred);
            if (pred) posd[wid][base + __popcll(m & ((1ull << lane) - 1ull))] = drow[wid][j];
            base += __popcll(m);
        }
        if (lane == 0) npos_s[wid] = base;
    }
    __syncthreads();

    // ---- P3: hinge accumulation, k = tid, all 4 anchors ----
    double sum = 0.0;
    int np_i = 0, nt_i = 0;
    #pragma unroll
    for (int a = 0; a < A; ++a) {
        const int li = liA[a];
        if (lk != li) {
            const float dik  = drow[a][tid];
            const int   npos = npos_s[a];
            #pragma unroll 4
            for (int p = 0; p < npos; ++p) {
                const float t = (posd[a][p] - dik) + MARGIN;  // reference op order
                if (t > EPS_T) { sum += (double)t; ++np_i; }
            }
            nt_i += npos;
        }
    }

    // ---- P4: fixed-tree reduction ----
    double s = sum, p = (double)np_i, t = (double)nt_i;
    #pragma unroll
    for (int off = 32; off > 0; off >>= 1) {
        s += __shfl_down(s, off);
        p += __shfl_down(p, off);
        t += __shfl_down(t, off);
    }
    if (lane == 0) { red[wid] = s; red[8 + wid] = p; red[16 + wid] = t; }
    __syncthreads();
    if (tid == 0) {
        double S = 0.0, P = 0.0, T = 0.0;
        #pragma unroll
        for (int w = 0; w < 8; ++w) { S += red[w]; P += red[8 + w]; T += red[16 + w]; }
        partial[blockIdx.x]            = S;
        partial[NBLK + blockIdx.x]     = P;
        partial[2 * NBLK + blockIdx.x] = T;
    }
}

__global__ __launch_bounds__(128) void triplet_final_k(
    const double* __restrict__ partial, float* __restrict__ out)
{
    __shared__ double red[6];
    const int tid  = threadIdx.x;
    const int lane = tid & 63;
    const int wid  = tid >> 6;
    double a = partial[tid];
    double b = partial[NBLK + tid];
    double c = partial[2 * NBLK + tid];
    #pragma unroll
    for (int off = 32; off > 0; off >>= 1) {
        a += __shfl_down(a, off);
        b += __shfl_down(b, off);
        c += __shfl_down(c, off);
    }
    if (lane == 0) { red[wid] = a; red[2 + wid] = b; red[4 + wid] = c; }
    __syncthreads();
    if (tid == 0) {
        const double S = red[0] + red[1];
        const double P = red[2] + red[3];
        const double T = red[4] + red[5];
        out[0] = (float)(S / (P + 1e-16));  // loss
        out[1] = (float)(P / (T + 1e-16));  // fraction_positive
    }
}

extern "C" void kernel_launch(void* const* d_in, const int* in_sizes, int n_in,
                              void* d_out, int out_size, void* d_ws, size_t ws_size,
                              hipStream_t stream) {
    const float* emb   = (const float*)d_in[0];   // [512,128] f32
    const int*   lab   = (const int*)d_in[1];     // [512] i32
    float*       out   = (float*)d_out;           // [2] f32: loss, fraction_positive
    double*      parts = (double*)d_ws;           // 3*NBLK doubles = 3 KB

    triplet_main_k<<<NBLK, 512, 0, stream>>>(emb, lab, parts);
    triplet_final_k<<<1, 128, 0, stream>>>(parts, out);
}

// Round 7
// 16.683 us; speedup vs baseline: 1.3329x; 1.3329x over previous
//
#include <hip/hip_runtime.h>

constexpr int N = 512;
constexpr int D = 128;
constexpr float MARGIN = 1.0f;
constexpr float EPS_T = 1e-16f;

// Two deterministic kernels. Main: one block per anchor, 512 threads.
//  P1: 8 passes; pass p, thread tid handles row r = p*64 + (tid>>3), lane-sub
//      sub = tid&7 reads float4 chunks {sub, sub+8, sub+16, sub+24} (coalesced,
//      8x128B segments per instr). NO cross-lane ops, NO LDS reads in the loop:
//      partial sq -> ds_write sqpart[p*512+tid] (stride-1, conflict-free).
//      Passes pipeline on independent global loads.
//  P1b: after one barrier, thread t sums its own row's 8 partials
//      (2x ds_read_b128 + 7 adds), safe-sqrt -> dik in REGISTER; also to drow.
//  P2: wave 0 ballot-compacts positive distances (deterministic order).
//  P3: thread's k (= tid) if negative: hinge over ~16 positives (LDS broadcast).
//  P4: fixed-tree f64 reduction -> per-block (sum, npos, ntrip).
// Final: one block reduces 512 triples -> two scalars.
__global__ __launch_bounds__(512, 2) void triplet_main_k(
    const float* __restrict__ emb, const int* __restrict__ labels,
    double* __restrict__ partial)
{
    __shared__ float  sqpart[8 * N];   // 16 KB: [pass][tid] partial sums
    __shared__ float  drow[N];
    __shared__ float  posd[N];
    __shared__ int    npos_s;
    __shared__ double red[24];         // [0..7]=sum, [8..15]=npos, [16..23]=ntrip

    const int i    = blockIdx.x;
    const int tid  = threadIdx.x;
    const int lane = tid & 63;
    const int wid  = tid >> 6;
    const int sub  = tid & 7;

    // anchor chunks -> registers (broadcast within each 8-lane group; L1-hot)
    const float4* ea = reinterpret_cast<const float4*>(emb + (size_t)i * D);
    float4 a0 = ea[sub], a1 = ea[sub + 8], a2 = ea[sub + 16], a3 = ea[sub + 24];

    const int lk = labels[tid];        // this thread's k-label
    const int li = labels[i];          // uniform broadcast

    // ---- P1: partial squared distances, fully pipelined ----
    #pragma unroll 4
    for (int p = 0; p < 8; ++p) {
        const int r = p * 64 + (tid >> 3);
        const float4* er = reinterpret_cast<const float4*>(emb + (size_t)r * D);
        float4 v0 = er[sub], v1 = er[sub + 8], v2 = er[sub + 16], v3 = er[sub + 24];
        float sq = 0.f;
        {
            float d0 = a0.x - v0.x, d1 = a0.y - v0.y, d2 = a0.z - v0.z, d3 = a0.w - v0.w;
            sq += d0 * d0 + d1 * d1 + d2 * d2 + d3 * d3;
        }
        {
            float d0 = a1.x - v1.x, d1 = a1.y - v1.y, d2 = a1.z - v1.z, d3 = a1.w - v1.w;
            sq += d0 * d0 + d1 * d1 + d2 * d2 + d3 * d3;
        }
        {
            float d0 = a2.x - v2.x, d1 = a2.y - v2.y, d2 = a2.z - v2.z, d3 = a2.w - v2.w;
            sq += d0 * d0 + d1 * d1 + d2 * d2 + d3 * d3;
        }
        {
            float d0 = a3.x - v3.x, d1 = a3.y - v3.y, d2 = a3.z - v3.z, d3 = a3.w - v3.w;
            sq += d0 * d0 + d1 * d1 + d2 * d2 + d3 * d3;
        }
        sqpart[p * 512 + tid] = sq;    // stride-1 ds_write, no dependent wait
    }
    __syncthreads();

    // ---- P1b: finish own row (row = tid) ----
    // partials for row t live at (t>>6)*512 + ((t&63)<<3) + {0..7}: contiguous.
    const int fbase = (tid >> 6) * 512 + ((tid & 63) << 3);
    const float4* fp = reinterpret_cast<const float4*>(&sqpart[fbase]);
    const float4 s0 = fp[0], s1 = fp[1];
    const float sq = ((s0.x + s0.y) + (s0.z + s0.w)) + ((s1.x + s1.y) + (s1.z + s1.w));
    const float dik = (sq > 0.f) ? sqrtf(sq) : 0.f;   // safe sqrt per reference
    drow[tid] = dik;
    __syncthreads();

    // ---- P2: deterministic positive-distance compaction (wave 0) ----
    if (wid == 0) {
        int base = 0;
        #pragma unroll
        for (int r = 0; r < 8; ++r) {
            const int j = r * 64 + lane;
            const bool pred = (labels[j] == li) && (j != i);
            const unsigned long long m = __ballot(pred);
            if (pred) posd[base + __popcll(m & ((1ull << lane) - 1ull))] = drow[j];
            base += __popcll(m);
        }
        if (lane == 0) npos_s = base;
    }
    __syncthreads();

    // ---- P3: hinge accumulation (this thread's k a negative?) ----
    const int npos = npos_s;
    double sum = 0.0;
    int np_i = 0, nt_i = 0;
    if (lk != li) {
        #pragma unroll 4
        for (int p = 0; p < npos; ++p) {
            const float t = (posd[p] - dik) + MARGIN;  // reference op order
            if (t > EPS_T) { sum += (double)t; ++np_i; }
        }
        nt_i = npos;
    }

    // ---- P4: fixed-tree reduction ----
    double s = sum, p = (double)np_i, t = (double)nt_i;
    #pragma unroll
    for (int off = 32; off > 0; off >>= 1) {
        s += __shfl_down(s, off);
        p += __shfl_down(p, off);
        t += __shfl_down(t, off);
    }
    if (lane == 0) { red[wid] = s; red[8 + wid] = p; red[16 + wid] = t; }
    __syncthreads();
    if (tid == 0) {
        double S = 0.0, P = 0.0, T = 0.0;
        #pragma unroll
        for (int w = 0; w < 8; ++w) { S += red[w]; P += red[8 + w]; T += red[16 + w]; }
        partial[i]         = S;
        partial[N + i]     = P;
        partial[2 * N + i] = T;
    }
}

__global__ __launch_bounds__(512) void triplet_final_k(
    const double* __restrict__ partial, float* __restrict__ out)
{
    __shared__ double red[24];
    const int tid  = threadIdx.x;
    const int lane = tid & 63;
    const int wid  = tid >> 6;
    double a = partial[tid];
    double b = partial[N + tid];
    double c = partial[2 * N + tid];
    #pragma unroll
    for (int off = 32; off > 0; off >>= 1) {
        a += __shfl_down(a, off);
        b += __shfl_down(b, off);
        c += __shfl_down(c, off);
    }
    if (lane == 0) { red[wid] = a; red[8 + wid] = b; red[16 + wid] = c; }
    __syncthreads();
    if (tid == 0) {
        double S = 0.0, P = 0.0, T = 0.0;
        #pragma unroll
        for (int w = 0; w < 8; ++w) { S += red[w]; P += red[8 + w]; T += red[16 + w]; }
        out[0] = (float)(S / (P + 1e-16));  // loss
        out[1] = (float)(P / (T + 1e-16));  // fraction_positive
    }
}

extern "C" void kernel_launch(void* const* d_in, const int* in_sizes, int n_in,
                              void* d_out, int out_size, void* d_ws, size_t ws_size,
                              hipStream_t stream) {
    const float* emb   = (const float*)d_in[0];   // [512,128] f32
    const int*   lab   = (const int*)d_in[1];     // [512] i32
    float*       out   = (float*)d_out;           // [2] f32: loss, fraction_positive
    double*      parts = (double*)d_ws;           // 3*N doubles = 12 KB

    triplet_main_k<<<N, 512, 0, stream>>>(emb, lab, parts);
    triplet_final_k<<<1, 512, 0, stream>>>(parts, out);
}